// Round 12
// baseline (287.758 us; speedup 1.0000x reference)
//
#include <hip/hip_runtime.h>
#include <hip/hip_bf16.h>
#include <hip/hip_cooperative_groups.h>

// GNN attention layer (GAT-style), MI355X gfx950.
// R12: (1) 5-pass partition fused into ONE cooperative kernel (4 grid syncs)
//      (2) aggregate unrolled to 16 edges/iter (Poisson(16) -> 1 iter typical,
//          2x outstanding gathers on the L2-miss path)
//      (3) proj PBLK 256->512 (2 blocks/CU for x-stream latency cover)
//      proj math / fp8 kv / exact CSR unchanged from R11.

#define N_NODES 50000
#define E_EDGES 800000
#define IN_DIM  128
#define HD      128   // H*D = 2*64
#define NPB     256   // nodes per bin
#define NB      196   // ceil(N_NODES / NPB)
#define EB      2048  // edges per partition block
#define NBLK_AC ((E_EDGES + EB - 1) / EB)   // 391
#define NTILES  ((N_NODES + 63) / 64)       // 782
#define PBLK    512                          // proj blocks
#define PSCALE  0.18033688011112042f         // (1/sqrt(64)) * log2(e)

typedef float  f32x4  __attribute__((ext_vector_type(4)));
typedef float  f32x2  __attribute__((ext_vector_type(2)));
typedef __bf16 bf16x8 __attribute__((ext_vector_type(8)));
typedef unsigned short u16x8 __attribute__((ext_vector_type(8)));

__device__ __forceinline__ float bf2f(unsigned short u) {
    return __uint_as_float((unsigned int)u << 16);
}

// ---------------------------------------------------------------------------
// Kernel A: projections. q,s bf16; k,v fp8 interleaved per node row (256B).
// ---------------------------------------------------------------------------
__global__ __launch_bounds__(512) void proj_kernel(
    const float* __restrict__ x,
    const float* __restrict__ Wq, const float* __restrict__ bq,
    const float* __restrict__ Wk, const float* __restrict__ bk,
    const float* __restrict__ Wv, const float* __restrict__ bv,
    const float* __restrict__ Ws, const float* __restrict__ bs,
    __bf16* __restrict__ qb, unsigned char* __restrict__ kv8,
    __bf16* __restrict__ sbuf)
{
    __shared__ __bf16 xs[64][136];   // +8 pad

    const int tid  = threadIdx.x;
    const int lane = tid & 63;
    const int wave = tid >> 6;       // 0..7
    const int l15  = lane & 15;
    const int g    = lane >> 4;

    const int p    = wave >> 1;
    const int colh = (wave & 1) * 64;
    const float* Wp     = (p == 0) ? Wq : (p == 1) ? Wk : (p == 2) ? Wv : Ws;
    const float* bias_p = (p == 0) ? bq : (p == 1) ? bk : (p == 2) ? bv : bs;

    bf16x8 Bf[4][4];   // [ks][cf], built once from fp32 W
    #pragma unroll
    for (int ks = 0; ks < 4; ++ks) {
        #pragma unroll
        for (int cf = 0; cf < 4; ++cf) {
            bf16x8 b;
            #pragma unroll
            for (int j = 0; j < 8; ++j)
                b[j] = (__bf16)Wp[(size_t)(ks * 32 + g * 8 + j) * HD + colh + cf * 16 + l15];
            Bf[ks][cf] = b;
        }
    }

    float bias_v[4];
    #pragma unroll
    for (int cf = 0; cf < 4; ++cf) bias_v[cf] = bias_p[colh + cf * 16 + l15];

    const int srow = tid >> 5;
    const int sc4  = tid & 31;

    int t = blockIdx.x;
    float4 pre[4];
    if (t < NTILES) {
        #pragma unroll
        for (int it = 0; it < 4; ++it) {
            int row  = it * 16 + srow;
            int grow = t * 64 + row;
            pre[it] = (grow < N_NODES) ? *(const float4*)(x + (size_t)grow * IN_DIM + sc4 * 4)
                                       : make_float4(0.f, 0.f, 0.f, 0.f);
        }
    }

    for (; t < NTILES; t += PBLK) {
        __syncthreads();
        #pragma unroll
        for (int it = 0; it < 4; ++it) {
            int row = it * 16 + srow;
            __bf16* dst = &xs[row][sc4 * 4];
            dst[0] = (__bf16)pre[it].x; dst[1] = (__bf16)pre[it].y;
            dst[2] = (__bf16)pre[it].z; dst[3] = (__bf16)pre[it].w;
        }
        __syncthreads();

        int tn = t + PBLK;
        if (tn < NTILES) {
            #pragma unroll
            for (int it = 0; it < 4; ++it) {
                int row  = it * 16 + srow;
                int grow = tn * 64 + row;
                pre[it] = (grow < N_NODES) ? *(const float4*)(x + (size_t)grow * IN_DIM + sc4 * 4)
                                           : make_float4(0.f, 0.f, 0.f, 0.f);
            }
        }

        f32x4 acc[4][4];
        #pragma unroll
        for (int i = 0; i < 4; ++i)
            #pragma unroll
            for (int j = 0; j < 4; ++j) acc[i][j] = (f32x4){0.f, 0.f, 0.f, 0.f};

        #pragma unroll
        for (int ks = 0; ks < 4; ++ks) {
            #pragma unroll
            for (int rf = 0; rf < 4; ++rf) {
                bf16x8 A = *(const bf16x8*)&xs[rf * 16 + l15][ks * 32 + g * 8];
                #pragma unroll
                for (int cf = 0; cf < 4; ++cf)
                    acc[rf][cf] = __builtin_amdgcn_mfma_f32_16x16x32_bf16(A, Bf[ks][cf], acc[rf][cf], 0, 0, 0);
            }
        }

        const int nodebase = t * 64;
        if (p == 0 || p == 3) {
            __bf16* outp = (p == 0) ? qb : sbuf;
            #pragma unroll
            for (int cf = 0; cf < 4; ++cf) {
                int col = colh + cf * 16 + l15;
                #pragma unroll
                for (int rf = 0; rf < 4; ++rf) {
                    #pragma unroll
                    for (int r = 0; r < 4; ++r) {
                        int grow = nodebase + rf * 16 + g * 4 + r;
                        if (grow < N_NODES)
                            outp[(size_t)grow * HD + col] = (__bf16)(acc[rf][cf][r] + bias_v[cf]);
                    }
                }
            }
        } else {
            unsigned char* outp = kv8 + ((p == 2) ? 128 : 0);
            #pragma unroll
            for (int cf = 0; cf < 4; ++cf) {
                int col = colh + cf * 16 + l15;
                #pragma unroll
                for (int rf = 0; rf < 4; ++rf) {
                    #pragma unroll
                    for (int r = 0; r < 4; ++r) {
                        int grow = nodebase + rf * 16 + g * 4 + r;
                        if (grow < N_NODES) {
                            float val = acc[rf][cf][r] + bias_v[cf];
                            unsigned int pk = __builtin_amdgcn_cvt_pk_fp8_f32(val, val, 0, false);
                            outp[(size_t)grow * 256 + col] = (unsigned char)(pk & 0xff);
                        }
                    }
                }
            }
        }
    }
}

// ---------------------------------------------------------------------------
// Cooperative partition kernel: hist -> scan(bin) -> scan(bins) -> scatter
// -> build, separated by grid syncs. 391 blocks x 256 threads.
// ---------------------------------------------------------------------------
__global__ __launch_bounds__(256) void partition_coop(
    const int* __restrict__ ei, int* __restrict__ hist, int* __restrict__ sums,
    int* __restrict__ binbase, int2* __restrict__ part,
    int* __restrict__ slot, int* __restrict__ nbase)
{
    namespace cg = cooperative_groups;
    cg::grid_group grid = cg::this_grid();
    __shared__ int sh[768];
    const int tid = threadIdx.x;
    const int blk = blockIdx.x;
    const int base = blk * EB;
    const int* srcs = ei;
    const int* dsts = ei + E_EDGES;

    // ---- P1: per-block histogram over NB bins ----
    for (int i = tid; i < NB; i += 256) sh[i] = 0;
    __syncthreads();
    #pragma unroll
    for (int half = 0; half < 2; ++half) {
        int e0 = base + half * 1024 + tid * 4;
        if (e0 + 3 < E_EDGES) {
            int4 d = *(const int4*)(dsts + e0);
            atomicAdd(&sh[d.x >> 8], 1);
            atomicAdd(&sh[d.y >> 8], 1);
            atomicAdd(&sh[d.z >> 8], 1);
            atomicAdd(&sh[d.w >> 8], 1);
        } else {
            for (int j = 0; j < 4; ++j)
                if (e0 + j < E_EDGES) atomicAdd(&sh[dsts[e0 + j] >> 8], 1);
        }
    }
    __syncthreads();
    for (int i = tid; i < NB; i += 256)
        hist[i * NBLK_AC + blk] = sh[i];
    grid.sync();

    // ---- P2: blocks 0..NB-1 scan their bin's NBLK_AC counts ----
    if (blk < NB) {
        int* hb = hist + (size_t)blk * NBLK_AC;
        sh[tid]       = (tid       < NBLK_AC) ? hb[tid]       : 0;
        sh[tid + 256] = (tid + 256 < NBLK_AC) ? hb[tid + 256] : 0;
        __syncthreads();
        #pragma unroll
        for (int d = 1; d < 512; d <<= 1) {
            int v0 = sh[tid],       u0 = (tid       >= d) ? sh[tid - d]       : 0;
            int v1 = sh[tid + 256], u1 = (tid + 256 >= d) ? sh[tid + 256 - d] : 0;
            __syncthreads();
            sh[tid] = v0 + u0; sh[tid + 256] = v1 + u1;
            __syncthreads();
        }
        if (tid < NBLK_AC)       hb[tid]       = (tid == 0) ? 0 : sh[tid - 1];
        if (tid + 256 < NBLK_AC) hb[tid + 256] = sh[tid + 255];
        if (tid == 0) sums[blk] = sh[NBLK_AC - 1];
    }
    grid.sync();

    // ---- P3: block 0 scans the NB bin sums -> binbase ----
    if (blk == 0) {
        sh[tid] = (tid < NB) ? sums[tid] : 0;
        __syncthreads();
        #pragma unroll
        for (int d = 1; d < 256; d <<= 1) {
            int v = sh[tid];
            int u = (tid >= d) ? sh[tid - d] : 0;
            __syncthreads();
            sh[tid] = v + u;
            __syncthreads();
        }
        if (tid < NB) binbase[tid] = (tid == 0) ? 0 : sh[tid - 1];
        if (tid == 0) binbase[NB] = sh[255];
    }
    grid.sync();

    // ---- P4: scatter (src,dst) into bin-partitioned part[] ----
    {
        int* hb2 = sh;          // absolute base per bin for this block
        int* h2  = sh + 256;    // running rank
        for (int i = tid; i < NB; i += 256) {
            hb2[i] = hist[i * NBLK_AC + blk] + binbase[i];
            h2[i]  = 0;
        }
        __syncthreads();
        #pragma unroll
        for (int half = 0; half < 2; ++half) {
            int e0 = base + half * 1024 + tid * 4;
            if (e0 + 3 < E_EDGES) {
                int4 s4 = *(const int4*)(srcs + e0);
                int4 d4 = *(const int4*)(dsts + e0);
                int bin, r;
                bin = d4.x >> 8; r = atomicAdd(&h2[bin], 1); part[hb2[bin] + r] = make_int2(s4.x, d4.x);
                bin = d4.y >> 8; r = atomicAdd(&h2[bin], 1); part[hb2[bin] + r] = make_int2(s4.y, d4.y);
                bin = d4.z >> 8; r = atomicAdd(&h2[bin], 1); part[hb2[bin] + r] = make_int2(s4.z, d4.z);
                bin = d4.w >> 8; r = atomicAdd(&h2[bin], 1); part[hb2[bin] + r] = make_int2(s4.w, d4.w);
            } else {
                for (int j = 0; j < 4; ++j) {
                    if (e0 + j < E_EDGES) {
                        int sv = srcs[e0 + j], dv = dsts[e0 + j];
                        int bin = dv >> 8;
                        int r = atomicAdd(&h2[bin], 1);
                        part[hb2[bin] + r] = make_int2(sv, dv);
                    }
                }
            }
        }
    }
    grid.sync();

    // ---- P5: blocks 0..NB-1 build exact CSR for their bin ----
    if (blk < NB) {
        int* cnt2 = sh;
        int* pfx  = sh + 256;
        int* ofs  = sh + 512;
        const int lo = binbase[blk];
        const int hi = binbase[blk + 1];
        const int n0 = blk * NPB;

        cnt2[tid] = 0;
        __syncthreads();
        for (int i = lo + tid; i < hi; i += 256)
            atomicAdd(&cnt2[part[i].y - n0], 1);
        __syncthreads();

        pfx[tid] = cnt2[tid];
        __syncthreads();
        #pragma unroll
        for (int d = 1; d < NPB; d <<= 1) {
            int v = pfx[tid];
            int u = (tid >= d) ? pfx[tid - d] : 0;
            __syncthreads();
            pfx[tid] = v + u;
            __syncthreads();
        }
        const int excl = pfx[tid] - cnt2[tid];
        ofs[tid] = excl;
        const int node = n0 + tid;
        if (node < N_NODES) nbase[node] = lo + excl;
        if (blk == NB - 1 && tid == 0) nbase[N_NODES] = E_EDGES;
        __syncthreads();

        for (int i = lo + tid; i < hi; i += 256) {
            int2 e = part[i];
            int r = atomicAdd(&ofs[e.y - n0], 1);
            slot[lo + r] = e.x;
        }
    }
}

// ---------------------------------------------------------------------------
// Aggregation: wave = 2 nodes x 2 edge-slots; lane owns 8 cols; 16 edges/iter
// (one iteration for typical Poisson(16) degree). k/v fp8, exact CSR.
// ---------------------------------------------------------------------------
__global__ __launch_bounds__(256) void aggregate_kernel(
    const __bf16* __restrict__ qb, const unsigned char* __restrict__ kv8,
    const __bf16* __restrict__ sbuf,
    const int* __restrict__ nbase, const int* __restrict__ slot,
    float* __restrict__ out)
{
    const int tid  = threadIdx.x;
    const int lane = tid & 63;
    const int wave = tid >> 6;
    const int h    = lane >> 5;      // node of the pair
    const int lh   = lane & 31;
    const int s    = lh >> 4;        // edge slot (0/1)
    const int l16  = lh & 15;        // owns cols 8*l16 .. 8*l16+7
    const int node = blockIdx.x * 8 + wave * 2 + h;
    const bool nvalid = node < N_NODES;
    const int nc = nvalid ? node : 0;

    const int bse = nbase[nc];
    const int deg = nvalid ? (nbase[nc + 1] - bse) : 0;

    u16x8 qu = *(const u16x8*)(qb + (size_t)nc * HD + 8 * l16);
    float qf[8];
    #pragma unroll
    for (int c = 0; c < 8; ++c) qf[c] = bf2f(qu[c]);

    int my_src = (lh < deg) ? slot[bse + lh] : 0;

    float lsum = 0.f;
    float acc[8];
    #pragma unroll
    for (int c = 0; c < 8; ++c) acc[c] = 0.f;

    const int sbase = h * 32;
    for (int i = 0; i < deg; i += 16) {
        int  jj[8], se[8];
        uint2 kr[8], vr[8];
        float d[8];

        #pragma unroll
        for (int r = 0; r < 8; ++r) {
            jj[r] = i + 2 * r + s;                        // per-lane ordinal
            int sv = __shfl(my_src, sbase + (jj[r] & 31), 64);
            if (jj[r] >= 32) sv = slot[bse + jj[r]];      // rare (deg>32) path
            se[r] = (jj[r] < deg) ? sv : 0;
        }
        #pragma unroll
        for (int r = 0; r < 8; ++r) {
            const unsigned char* rowp = kv8 + (size_t)se[r] * 256 + 8 * l16;
            kr[r] = *(const uint2*)rowp;           // k fp8 x8
            vr[r] = *(const uint2*)(rowp + 128);   // v fp8 x8
        }
        #pragma unroll
        for (int r = 0; r < 8; ++r) {
            f32x2 ka = __builtin_amdgcn_cvt_pk_f32_fp8(kr[r].x, 0);
            f32x2 kb_ = __builtin_amdgcn_cvt_pk_f32_fp8(kr[r].x, 1);
            f32x2 kc = __builtin_amdgcn_cvt_pk_f32_fp8(kr[r].y, 0);
            f32x2 kd = __builtin_amdgcn_cvt_pk_f32_fp8(kr[r].y, 1);
            d[r] = qf[0] * ka.x + qf[1] * ka.y + qf[2] * kb_.x + qf[3] * kb_.y
                 + qf[4] * kc.x + qf[5] * kc.y + qf[6] * kd.x + qf[7] * kd.y;
        }
        #pragma unroll
        for (int m = 1; m <= 4; m <<= 1) {
            #pragma unroll
            for (int r = 0; r < 8; ++r)
                d[r] += __shfl_xor(d[r], m);
        }
        #pragma unroll
        for (int r = 0; r < 8; ++r) {
            float a2 = (jj[r] < deg) ? d[r] * PSCALE : -INFINITY;
            float p  = exp2f(a2);                // == exp(alpha), exp2(-inf)=0
            lsum += p;
            f32x2 va = __builtin_amdgcn_cvt_pk_f32_fp8(vr[r].x, 0);
            f32x2 vb_ = __builtin_amdgcn_cvt_pk_f32_fp8(vr[r].x, 1);
            f32x2 vc = __builtin_amdgcn_cvt_pk_f32_fp8(vr[r].y, 0);
            f32x2 vd = __builtin_amdgcn_cvt_pk_f32_fp8(vr[r].y, 1);
            acc[0] += p * va.x;  acc[1] += p * va.y;
            acc[2] += p * vb_.x; acc[3] += p * vb_.y;
            acc[4] += p * vc.x;  acc[5] += p * vc.y;
            acc[6] += p * vd.x;  acc[7] += p * vd.y;
        }
    }

    lsum += __shfl_xor(lsum, 16);
    #pragma unroll
    for (int c = 0; c < 8; ++c) acc[c] += __shfl_xor(acc[c], 16);

    float inv = (deg > 0) ? 1.f / (lsum + 1e-16f) : 0.f;
    u16x8 su = *(const u16x8*)(sbuf + (size_t)nc * HD + 8 * l16);

    f32x4 ov;
    #pragma unroll
    for (int cc = 0; cc < 4; ++cc) {
        float av;
        unsigned short sv;
        switch (cc) {  // static indices; s-select via cndmask
            case 0: av = s ? acc[4] : acc[0]; sv = s ? su[4] : su[0]; break;
            case 1: av = s ? acc[5] : acc[1]; sv = s ? su[5] : su[1]; break;
            case 2: av = s ? acc[6] : acc[2]; sv = s ? su[6] : su[2]; break;
            default: av = s ? acc[7] : acc[3]; sv = s ? su[7] : su[3]; break;
        }
        ov[cc] = fmaxf(av * inv + bf2f(sv), 0.f);
    }
    if (nvalid)
        *(f32x4*)(out + (size_t)node * HD + 8 * l16 + 4 * s) = ov;
}

// ---------------------------------------------------------------------------
extern "C" void kernel_launch(void* const* d_in, const int* in_sizes, int n_in,
                              void* d_out, int out_size, void* d_ws, size_t ws_size,
                              hipStream_t stream)
{
    const float* x  = (const float*)d_in[0];
    const int*   ei = (const int*)d_in[1];
    const float* Wq = (const float*)d_in[2];
    const float* bq = (const float*)d_in[3];
    const float* Wk = (const float*)d_in[4];
    const float* bk = (const float*)d_in[5];
    const float* Wv = (const float*)d_in[6];
    const float* bv = (const float*)d_in[7];
    const float* Ws = (const float*)d_in[8];
    const float* bs = (const float*)d_in[9];

    char* ws = (char*)d_ws;
    size_t off = 0;
    auto alloc = [&](size_t bytes) {
        void* p = ws + off;
        off += (bytes + 255) & ~(size_t)255;
        return p;
    };
    const size_t projB = (size_t)N_NODES * HD * sizeof(__bf16);  // 12.8 MB
    __bf16* qb = (__bf16*)alloc(projB);
    unsigned char* kv8 = (unsigned char*)alloc((size_t)N_NODES * 256);
    __bf16* sbf = (__bf16*)alloc(projB);
    int* hist    = (int*)alloc((size_t)NB * NBLK_AC * sizeof(int));   // 306 KB
    int* sums    = (int*)alloc((size_t)NB * sizeof(int));
    int* binbase = (int*)alloc((size_t)(NB + 1) * sizeof(int));
    int2* part   = (int2*)alloc((size_t)E_EDGES * sizeof(int2));      // 6.4 MB
    int* slot    = (int*)alloc((size_t)E_EDGES * sizeof(int));        // 3.2 MB
    int* nbase   = (int*)alloc((size_t)(N_NODES + 1) * sizeof(int));  // 200 KB

    void* cargs[] = { (void*)&ei, (void*)&hist, (void*)&sums, (void*)&binbase,
                      (void*)&part, (void*)&slot, (void*)&nbase };
    hipLaunchCooperativeKernel((void*)partition_coop, dim3(NBLK_AC), dim3(256),
                               cargs, 0, stream);

    proj_kernel<<<PBLK, 512, 0, stream>>>(
        x, Wq, bq, Wk, bk, Wv, bv, Ws, bs, qb, kv8, sbf);

    aggregate_kernel<<<(N_NODES + 7) / 8, 256, 0, stream>>>(
        qb, kv8, sbf, nbase, slot, (float*)d_out);
}

// Round 13
// 97.341 us; speedup vs baseline: 2.9562x; 2.9562x over previous
//
#include <hip/hip_runtime.h>
#include <hip/hip_bf16.h>

// GNN attention layer (GAT-style), MI355X gfx950.
// R13: revert R12's cooperative fusion (grid.sync cost ~190us on MI355X —
//      separate launches are near-free by comparison). Keep R11's 5-kernel
//      atomic-free partition. Retain R12's micro-changes for isolation:
//      aggregate 16 edges/iter; proj PBLK=512.

#define N_NODES 50000
#define E_EDGES 800000
#define IN_DIM  128
#define HD      128   // H*D = 2*64
#define NPB     256   // nodes per bin
#define NB      196   // ceil(N_NODES / NPB)
#define EB      2048  // edges per block in passes A/C
#define NBLK_AC ((E_EDGES + EB - 1) / EB)   // 391
#define NTILES  ((N_NODES + 63) / 64)       // 782
#define PBLK    512                          // proj blocks
#define PSCALE  0.18033688011112042f         // (1/sqrt(64)) * log2(e)

typedef float  f32x4  __attribute__((ext_vector_type(4)));
typedef float  f32x2  __attribute__((ext_vector_type(2)));
typedef __bf16 bf16x8 __attribute__((ext_vector_type(8)));
typedef unsigned short u16x8 __attribute__((ext_vector_type(8)));

__device__ __forceinline__ float bf2f(unsigned short u) {
    return __uint_as_float((unsigned int)u << 16);
}

// ---------------------------------------------------------------------------
// Kernel A: projections. q,s bf16; k,v fp8 interleaved per node row (256B).
// ---------------------------------------------------------------------------
__global__ __launch_bounds__(512) void proj_kernel(
    const float* __restrict__ x,
    const float* __restrict__ Wq, const float* __restrict__ bq,
    const float* __restrict__ Wk, const float* __restrict__ bk,
    const float* __restrict__ Wv, const float* __restrict__ bv,
    const float* __restrict__ Ws, const float* __restrict__ bs,
    __bf16* __restrict__ qb, unsigned char* __restrict__ kv8,
    __bf16* __restrict__ sbuf)
{
    __shared__ __bf16 xs[64][136];   // +8 pad

    const int tid  = threadIdx.x;
    const int lane = tid & 63;
    const int wave = tid >> 6;       // 0..7
    const int l15  = lane & 15;
    const int g    = lane >> 4;

    const int p    = wave >> 1;
    const int colh = (wave & 1) * 64;
    const float* Wp     = (p == 0) ? Wq : (p == 1) ? Wk : (p == 2) ? Wv : Ws;
    const float* bias_p = (p == 0) ? bq : (p == 1) ? bk : (p == 2) ? bv : bs;

    bf16x8 Bf[4][4];   // [ks][cf], built once from fp32 W
    #pragma unroll
    for (int ks = 0; ks < 4; ++ks) {
        #pragma unroll
        for (int cf = 0; cf < 4; ++cf) {
            bf16x8 b;
            #pragma unroll
            for (int j = 0; j < 8; ++j)
                b[j] = (__bf16)Wp[(size_t)(ks * 32 + g * 8 + j) * HD + colh + cf * 16 + l15];
            Bf[ks][cf] = b;
        }
    }

    float bias_v[4];
    #pragma unroll
    for (int cf = 0; cf < 4; ++cf) bias_v[cf] = bias_p[colh + cf * 16 + l15];

    const int srow = tid >> 5;
    const int sc4  = tid & 31;

    int t = blockIdx.x;
    float4 pre[4];
    if (t < NTILES) {
        #pragma unroll
        for (int it = 0; it < 4; ++it) {
            int row  = it * 16 + srow;
            int grow = t * 64 + row;
            pre[it] = (grow < N_NODES) ? *(const float4*)(x + (size_t)grow * IN_DIM + sc4 * 4)
                                       : make_float4(0.f, 0.f, 0.f, 0.f);
        }
    }

    for (; t < NTILES; t += PBLK) {
        __syncthreads();
        #pragma unroll
        for (int it = 0; it < 4; ++it) {
            int row = it * 16 + srow;
            __bf16* dst = &xs[row][sc4 * 4];
            dst[0] = (__bf16)pre[it].x; dst[1] = (__bf16)pre[it].y;
            dst[2] = (__bf16)pre[it].z; dst[3] = (__bf16)pre[it].w;
        }
        __syncthreads();

        int tn = t + PBLK;
        if (tn < NTILES) {
            #pragma unroll
            for (int it = 0; it < 4; ++it) {
                int row  = it * 16 + srow;
                int grow = tn * 64 + row;
                pre[it] = (grow < N_NODES) ? *(const float4*)(x + (size_t)grow * IN_DIM + sc4 * 4)
                                           : make_float4(0.f, 0.f, 0.f, 0.f);
            }
        }

        f32x4 acc[4][4];
        #pragma unroll
        for (int i = 0; i < 4; ++i)
            #pragma unroll
            for (int j = 0; j < 4; ++j) acc[i][j] = (f32x4){0.f, 0.f, 0.f, 0.f};

        #pragma unroll
        for (int ks = 0; ks < 4; ++ks) {
            #pragma unroll
            for (int rf = 0; rf < 4; ++rf) {
                bf16x8 A = *(const bf16x8*)&xs[rf * 16 + l15][ks * 32 + g * 8];
                #pragma unroll
                for (int cf = 0; cf < 4; ++cf)
                    acc[rf][cf] = __builtin_amdgcn_mfma_f32_16x16x32_bf16(A, Bf[ks][cf], acc[rf][cf], 0, 0, 0);
            }
        }

        const int nodebase = t * 64;
        if (p == 0 || p == 3) {
            __bf16* outp = (p == 0) ? qb : sbuf;
            #pragma unroll
            for (int cf = 0; cf < 4; ++cf) {
                int col = colh + cf * 16 + l15;
                #pragma unroll
                for (int rf = 0; rf < 4; ++rf) {
                    #pragma unroll
                    for (int r = 0; r < 4; ++r) {
                        int grow = nodebase + rf * 16 + g * 4 + r;
                        if (grow < N_NODES)
                            outp[(size_t)grow * HD + col] = (__bf16)(acc[rf][cf][r] + bias_v[cf]);
                    }
                }
            }
        } else {
            unsigned char* outp = kv8 + ((p == 2) ? 128 : 0);
            #pragma unroll
            for (int cf = 0; cf < 4; ++cf) {
                int col = colh + cf * 16 + l15;
                #pragma unroll
                for (int rf = 0; rf < 4; ++rf) {
                    #pragma unroll
                    for (int r = 0; r < 4; ++r) {
                        int grow = nodebase + rf * 16 + g * 4 + r;
                        if (grow < N_NODES) {
                            float val = acc[rf][cf][r] + bias_v[cf];
                            unsigned int pk = __builtin_amdgcn_cvt_pk_fp8_f32(val, val, 0, false);
                            outp[(size_t)grow * 256 + col] = (unsigned char)(pk & 0xff);
                        }
                    }
                }
            }
        }
    }
}

// ---------------------------------------------------------------------------
// Pass A: per-block LDS histogram over NB bins (bin = dst>>8).
// ---------------------------------------------------------------------------
__global__ __launch_bounds__(256) void histA(
    const int* __restrict__ ei, int* __restrict__ hist)
{
    __shared__ int h[NB];
    const int tid = threadIdx.x;
    for (int i = tid; i < NB; i += 256) h[i] = 0;
    __syncthreads();

    const int* dsts = ei + E_EDGES;
    const int base = blockIdx.x * EB;
    #pragma unroll
    for (int half = 0; half < 2; ++half) {
        int e0 = base + half * 1024 + tid * 4;
        if (e0 + 3 < E_EDGES) {
            int4 d = *(const int4*)(dsts + e0);
            atomicAdd(&h[d.x >> 8], 1);
            atomicAdd(&h[d.y >> 8], 1);
            atomicAdd(&h[d.z >> 8], 1);
            atomicAdd(&h[d.w >> 8], 1);
        } else {
            for (int j = 0; j < 4; ++j)
                if (e0 + j < E_EDGES) atomicAdd(&h[dsts[e0 + j] >> 8], 1);
        }
    }
    __syncthreads();
    for (int i = tid; i < NB; i += 256)
        hist[i * NBLK_AC + blockIdx.x] = h[i];
}

// ---------------------------------------------------------------------------
// Pass B1: one block per bin. Parallel exclusive scan of NBLK_AC counts.
// ---------------------------------------------------------------------------
__global__ __launch_bounds__(256) void scanB1(
    int* __restrict__ hist, int* __restrict__ sums)
{
    __shared__ int a[512];
    const int tid = threadIdx.x;
    const int b   = blockIdx.x;
    int* hb = hist + (size_t)b * NBLK_AC;

    a[tid]       = (tid       < NBLK_AC) ? hb[tid]       : 0;
    a[tid + 256] = (tid + 256 < NBLK_AC) ? hb[tid + 256] : 0;
    __syncthreads();
    #pragma unroll
    for (int d = 1; d < 512; d <<= 1) {
        int v0 = a[tid],       u0 = (tid       >= d) ? a[tid - d]       : 0;
        int v1 = a[tid + 256], u1 = (tid + 256 >= d) ? a[tid + 256 - d] : 0;
        __syncthreads();
        a[tid] = v0 + u0; a[tid + 256] = v1 + u1;
        __syncthreads();
    }
    if (tid < NBLK_AC)       hb[tid]       = (tid == 0) ? 0 : a[tid - 1];
    if (tid + 256 < NBLK_AC) hb[tid + 256] = a[tid + 255];
    if (tid == 0) sums[b] = a[NBLK_AC - 1];
}

// ---------------------------------------------------------------------------
// Pass B2: single block, parallel exclusive scan over NB bin sums -> binbase.
// ---------------------------------------------------------------------------
__global__ __launch_bounds__(256) void scanB2(
    const int* __restrict__ sums, int* __restrict__ binbase)
{
    __shared__ int a[256];
    const int tid = threadIdx.x;
    a[tid] = (tid < NB) ? sums[tid] : 0;
    __syncthreads();
    #pragma unroll
    for (int d = 1; d < 256; d <<= 1) {
        int v = a[tid];
        int u = (tid >= d) ? a[tid - d] : 0;
        __syncthreads();
        a[tid] = v + u;
        __syncthreads();
    }
    if (tid < NB) binbase[tid] = (tid == 0) ? 0 : a[tid - 1];
    if (tid == 0) binbase[NB] = a[255];
}

// ---------------------------------------------------------------------------
// Pass C: scatter (src,dst) into bin-partitioned part[].
// ---------------------------------------------------------------------------
__global__ __launch_bounds__(256) void scatterC(
    const int* __restrict__ ei, const int* __restrict__ hist,
    const int* __restrict__ binbase, int2* __restrict__ part)
{
    __shared__ int hb[NB];
    __shared__ int h2[NB];
    const int tid = threadIdx.x;
    for (int i = tid; i < NB; i += 256) {
        hb[i] = hist[i * NBLK_AC + blockIdx.x] + binbase[i];
        h2[i] = 0;
    }
    __syncthreads();

    const int* srcs = ei;
    const int* dsts = ei + E_EDGES;
    const int base = blockIdx.x * EB;
    #pragma unroll
    for (int half = 0; half < 2; ++half) {
        int e0 = base + half * 1024 + tid * 4;
        if (e0 + 3 < E_EDGES) {
            int4 s4 = *(const int4*)(srcs + e0);
            int4 d4 = *(const int4*)(dsts + e0);
            int bin, r;
            bin = d4.x >> 8; r = atomicAdd(&h2[bin], 1); part[hb[bin] + r] = make_int2(s4.x, d4.x);
            bin = d4.y >> 8; r = atomicAdd(&h2[bin], 1); part[hb[bin] + r] = make_int2(s4.y, d4.y);
            bin = d4.z >> 8; r = atomicAdd(&h2[bin], 1); part[hb[bin] + r] = make_int2(s4.z, d4.z);
            bin = d4.w >> 8; r = atomicAdd(&h2[bin], 1); part[hb[bin] + r] = make_int2(s4.w, d4.w);
        } else {
            for (int j = 0; j < 4; ++j) {
                if (e0 + j < E_EDGES) {
                    int sv = srcs[e0 + j], dv = dsts[e0 + j];
                    int bin = dv >> 8;
                    int r = atomicAdd(&h2[bin], 1);
                    part[hb[bin] + r] = make_int2(sv, dv);
                }
            }
        }
    }
}

// ---------------------------------------------------------------------------
// Pass D: one block per bin. Exact per-node counts + scan -> compacted CSR.
// ---------------------------------------------------------------------------
__global__ __launch_bounds__(256) void buildD(
    const int2* __restrict__ part, const int* __restrict__ binbase,
    int* __restrict__ slot, int* __restrict__ nbase)
{
    __shared__ int cnt2[NPB];
    __shared__ int pfx[NPB];
    __shared__ int ofs[NPB];
    const int tid = threadIdx.x;
    const int b   = blockIdx.x;
    const int lo  = binbase[b];
    const int hi  = binbase[b + 1];
    const int n0  = b * NPB;

    cnt2[tid] = 0;
    __syncthreads();
    for (int i = lo + tid; i < hi; i += 256)
        atomicAdd(&cnt2[part[i].y - n0], 1);
    __syncthreads();

    pfx[tid] = cnt2[tid];
    __syncthreads();
    #pragma unroll
    for (int d = 1; d < NPB; d <<= 1) {
        int v = pfx[tid];
        int u = (tid >= d) ? pfx[tid - d] : 0;
        __syncthreads();
        pfx[tid] = v + u;
        __syncthreads();
    }
    const int excl = pfx[tid] - cnt2[tid];
    ofs[tid] = excl;
    const int node = n0 + tid;
    if (node < N_NODES) nbase[node] = lo + excl;
    if (b == NB - 1 && tid == 0) nbase[N_NODES] = E_EDGES;
    __syncthreads();

    for (int i = lo + tid; i < hi; i += 256) {
        int2 e = part[i];
        int r = atomicAdd(&ofs[e.y - n0], 1);
        slot[lo + r] = e.x;
    }
}

// ---------------------------------------------------------------------------
// Aggregation: wave = 2 nodes x 2 edge-slots; lane owns 8 cols; 16 edges/iter.
// k/v fp8, exact CSR.
// ---------------------------------------------------------------------------
__global__ __launch_bounds__(256) void aggregate_kernel(
    const __bf16* __restrict__ qb, const unsigned char* __restrict__ kv8,
    const __bf16* __restrict__ sbuf,
    const int* __restrict__ nbase, const int* __restrict__ slot,
    float* __restrict__ out)
{
    const int tid  = threadIdx.x;
    const int lane = tid & 63;
    const int wave = tid >> 6;
    const int h    = lane >> 5;      // node of the pair
    const int lh   = lane & 31;
    const int s    = lh >> 4;        // edge slot (0/1)
    const int l16  = lh & 15;        // owns cols 8*l16 .. 8*l16+7
    const int node = blockIdx.x * 8 + wave * 2 + h;
    const bool nvalid = node < N_NODES;
    const int nc = nvalid ? node : 0;

    const int bse = nbase[nc];
    const int deg = nvalid ? (nbase[nc + 1] - bse) : 0;

    u16x8 qu = *(const u16x8*)(qb + (size_t)nc * HD + 8 * l16);
    float qf[8];
    #pragma unroll
    for (int c = 0; c < 8; ++c) qf[c] = bf2f(qu[c]);

    int my_src = (lh < deg) ? slot[bse + lh] : 0;

    float lsum = 0.f;
    float acc[8];
    #pragma unroll
    for (int c = 0; c < 8; ++c) acc[c] = 0.f;

    const int sbase = h * 32;
    for (int i = 0; i < deg; i += 16) {
        int  jj[8], se[8];
        uint2 kr[8], vr[8];
        float d[8];

        #pragma unroll
        for (int r = 0; r < 8; ++r) {
            jj[r] = i + 2 * r + s;                        // per-lane ordinal
            int sv = __shfl(my_src, sbase + (jj[r] & 31), 64);
            if (jj[r] >= 32) sv = slot[bse + jj[r]];      // rare (deg>32) path
            se[r] = (jj[r] < deg) ? sv : 0;
        }
        #pragma unroll
        for (int r = 0; r < 8; ++r) {
            const unsigned char* rowp = kv8 + (size_t)se[r] * 256 + 8 * l16;
            kr[r] = *(const uint2*)rowp;           // k fp8 x8
            vr[r] = *(const uint2*)(rowp + 128);   // v fp8 x8
        }
        #pragma unroll
        for (int r = 0; r < 8; ++r) {
            f32x2 ka = __builtin_amdgcn_cvt_pk_f32_fp8(kr[r].x, 0);
            f32x2 kb_ = __builtin_amdgcn_cvt_pk_f32_fp8(kr[r].x, 1);
            f32x2 kc = __builtin_amdgcn_cvt_pk_f32_fp8(kr[r].y, 0);
            f32x2 kd = __builtin_amdgcn_cvt_pk_f32_fp8(kr[r].y, 1);
            d[r] = qf[0] * ka.x + qf[1] * ka.y + qf[2] * kb_.x + qf[3] * kb_.y
                 + qf[4] * kc.x + qf[5] * kc.y + qf[6] * kd.x + qf[7] * kd.y;
        }
        #pragma unroll
        for (int m = 1; m <= 4; m <<= 1) {
            #pragma unroll
            for (int r = 0; r < 8; ++r)
                d[r] += __shfl_xor(d[r], m);
        }
        #pragma unroll
        for (int r = 0; r < 8; ++r) {
            float a2 = (jj[r] < deg) ? d[r] * PSCALE : -INFINITY;
            float p  = exp2f(a2);                // == exp(alpha), exp2(-inf)=0
            lsum += p;
            f32x2 va = __builtin_amdgcn_cvt_pk_f32_fp8(vr[r].x, 0);
            f32x2 vb_ = __builtin_amdgcn_cvt_pk_f32_fp8(vr[r].x, 1);
            f32x2 vc = __builtin_amdgcn_cvt_pk_f32_fp8(vr[r].y, 0);
            f32x2 vd = __builtin_amdgcn_cvt_pk_f32_fp8(vr[r].y, 1);
            acc[0] += p * va.x;  acc[1] += p * va.y;
            acc[2] += p * vb_.x; acc[3] += p * vb_.y;
            acc[4] += p * vc.x;  acc[5] += p * vc.y;
            acc[6] += p * vd.x;  acc[7] += p * vd.y;
        }
    }

    lsum += __shfl_xor(lsum, 16);
    #pragma unroll
    for (int c = 0; c < 8; ++c) acc[c] += __shfl_xor(acc[c], 16);

    float inv = (deg > 0) ? 1.f / (lsum + 1e-16f) : 0.f;
    u16x8 su = *(const u16x8*)(sbuf + (size_t)nc * HD + 8 * l16);

    f32x4 ov;
    #pragma unroll
    for (int cc = 0; cc < 4; ++cc) {
        float av;
        unsigned short sv;
        switch (cc) {  // static indices; s-select via cndmask
            case 0: av = s ? acc[4] : acc[0]; sv = s ? su[4] : su[0]; break;
            case 1: av = s ? acc[5] : acc[1]; sv = s ? su[5] : su[1]; break;
            case 2: av = s ? acc[6] : acc[2]; sv = s ? su[6] : su[2]; break;
            default: av = s ? acc[7] : acc[3]; sv = s ? su[7] : su[3]; break;
        }
        ov[cc] = fmaxf(av * inv + bf2f(sv), 0.f);
    }
    if (nvalid)
        *(f32x4*)(out + (size_t)node * HD + 8 * l16 + 4 * s) = ov;
}

// ---------------------------------------------------------------------------
extern "C" void kernel_launch(void* const* d_in, const int* in_sizes, int n_in,
                              void* d_out, int out_size, void* d_ws, size_t ws_size,
                              hipStream_t stream)
{
    const float* x  = (const float*)d_in[0];
    const int*   ei = (const int*)d_in[1];
    const float* Wq = (const float*)d_in[2];
    const float* bq = (const float*)d_in[3];
    const float* Wk = (const float*)d_in[4];
    const float* bk = (const float*)d_in[5];
    const float* Wv = (const float*)d_in[6];
    const float* bv = (const float*)d_in[7];
    const float* Ws = (const float*)d_in[8];
    const float* bs = (const float*)d_in[9];

    char* ws = (char*)d_ws;
    size_t off = 0;
    auto alloc = [&](size_t bytes) {
        void* p = ws + off;
        off += (bytes + 255) & ~(size_t)255;
        return p;
    };
    const size_t projB = (size_t)N_NODES * HD * sizeof(__bf16);  // 12.8 MB
    __bf16* qb = (__bf16*)alloc(projB);
    unsigned char* kv8 = (unsigned char*)alloc((size_t)N_NODES * 256);
    __bf16* sbf = (__bf16*)alloc(projB);
    int* hist    = (int*)alloc((size_t)NB * NBLK_AC * sizeof(int));   // 306 KB
    int* sums    = (int*)alloc((size_t)NB * sizeof(int));
    int* binbase = (int*)alloc((size_t)(NB + 1) * sizeof(int));
    int2* part   = (int2*)alloc((size_t)E_EDGES * sizeof(int2));      // 6.4 MB
    int* slot    = (int*)alloc((size_t)E_EDGES * sizeof(int));        // 3.2 MB
    int* nbase   = (int*)alloc((size_t)(N_NODES + 1) * sizeof(int));  // 200 KB

    histA<<<NBLK_AC, 256, 0, stream>>>(ei, hist);
    scanB1<<<NB, 256, 0, stream>>>(hist, sums);
    scanB2<<<1, 256, 0, stream>>>(sums, binbase);
    scatterC<<<NBLK_AC, 256, 0, stream>>>(ei, hist, binbase, part);
    buildD<<<NB, 256, 0, stream>>>(part, binbase, slot, nbase);

    proj_kernel<<<PBLK, 512, 0, stream>>>(
        x, Wq, bq, Wk, bk, Wv, bv, Ws, bs, qb, kv8, sbf);

    aggregate_kernel<<<(N_NODES + 7) / 8, 256, 0, stream>>>(
        qb, kv8, sbf, nbase, slot, (float*)d_out);
}

// Round 14
// 90.228 us; speedup vs baseline: 3.1892x; 1.0788x over previous
//
#include <hip/hip_runtime.h>
#include <hip/hip_bf16.h>

// GNN attention layer (GAT-style), MI355X gfx950.
// R14: aggregate reverted to 8-edge/iter (16-edge refuted: occupancy 39.5%,
//      +5us) + direct slot loads (no shfl broadcast -> DS chain off the
//      address-gen critical path). histA fused into proj via block-role
//      split (no device atomics -> safe, unlike R8). Partition/scan chain
//      unchanged from R11.

#define N_NODES 50000
#define E_EDGES 800000
#define IN_DIM  128
#define HD      128   // H*D = 2*64
#define NPB     256   // nodes per bin
#define NB      196   // ceil(N_NODES / NPB)
#define EB      2048  // edges per block in hist/scatter passes
#define NBLK_AC ((E_EDGES + EB - 1) / EB)   // 391
#define NTILES  ((N_NODES + 63) / 64)       // 782
#define PBLK    512                          // proj blocks (fused kernel: [0,PBLK))
#define PSCALE  0.18033688011112042f         // (1/sqrt(64)) * log2(e)

typedef float  f32x4  __attribute__((ext_vector_type(4)));
typedef float  f32x2  __attribute__((ext_vector_type(2)));
typedef __bf16 bf16x8 __attribute__((ext_vector_type(8)));
typedef unsigned short u16x8 __attribute__((ext_vector_type(8)));

__device__ __forceinline__ float bf2f(unsigned short u) {
    return __uint_as_float((unsigned int)u << 16);
}

// ---------------------------------------------------------------------------
// Fused kernel: blocks [0,PBLK) = projections; blocks [PBLK,PBLK+NBLK_AC) =
// per-block LDS histogram over NB bins (bin = dst>>8). No device atomics in
// either role.
// ---------------------------------------------------------------------------
__global__ __launch_bounds__(512) void fused_proj_hist(
    const float* __restrict__ x,
    const float* __restrict__ Wq, const float* __restrict__ bq,
    const float* __restrict__ Wk, const float* __restrict__ bk,
    const float* __restrict__ Wv, const float* __restrict__ bv,
    const float* __restrict__ Ws, const float* __restrict__ bs,
    const int* __restrict__ ei, int* __restrict__ hist,
    __bf16* __restrict__ qb, unsigned char* __restrict__ kv8,
    __bf16* __restrict__ sbuf)
{
    const int tid = threadIdx.x;

    if (blockIdx.x >= PBLK) {
        // ---------------- hist role ----------------
        __shared__ int h[NB];
        const int blk = blockIdx.x - PBLK;
        for (int i = tid; i < NB; i += 512) h[i] = 0;
        __syncthreads();
        const int* dsts = ei + E_EDGES;
        int e0 = blk * EB + tid * 4;   // 512 threads x 4 = 2048 = EB
        if (e0 + 3 < E_EDGES) {
            int4 d = *(const int4*)(dsts + e0);
            atomicAdd(&h[d.x >> 8], 1);
            atomicAdd(&h[d.y >> 8], 1);
            atomicAdd(&h[d.z >> 8], 1);
            atomicAdd(&h[d.w >> 8], 1);
        } else {
            for (int j = 0; j < 4; ++j)
                if (e0 + j < E_EDGES) atomicAdd(&h[dsts[e0 + j] >> 8], 1);
        }
        __syncthreads();
        for (int i = tid; i < NB; i += 512)
            hist[i * NBLK_AC + blk] = h[i];
        return;
    }

    // ---------------- proj role ----------------
    __shared__ __bf16 xs[64][136];   // +8 pad

    const int lane = tid & 63;
    const int wave = tid >> 6;       // 0..7
    const int l15  = lane & 15;
    const int g    = lane >> 4;

    const int p    = wave >> 1;
    const int colh = (wave & 1) * 64;
    const float* Wp     = (p == 0) ? Wq : (p == 1) ? Wk : (p == 2) ? Wv : Ws;
    const float* bias_p = (p == 0) ? bq : (p == 1) ? bk : (p == 2) ? bv : bs;

    bf16x8 Bf[4][4];   // [ks][cf], built once from fp32 W (L2-resident)
    #pragma unroll
    for (int ks = 0; ks < 4; ++ks) {
        #pragma unroll
        for (int cf = 0; cf < 4; ++cf) {
            bf16x8 b;
            #pragma unroll
            for (int j = 0; j < 8; ++j)
                b[j] = (__bf16)Wp[(size_t)(ks * 32 + g * 8 + j) * HD + colh + cf * 16 + l15];
            Bf[ks][cf] = b;
        }
    }

    float bias_v[4];
    #pragma unroll
    for (int cf = 0; cf < 4; ++cf) bias_v[cf] = bias_p[colh + cf * 16 + l15];

    const int srow = tid >> 5;
    const int sc4  = tid & 31;

    int t = blockIdx.x;
    float4 pre[4];
    if (t < NTILES) {
        #pragma unroll
        for (int it = 0; it < 4; ++it) {
            int row  = it * 16 + srow;
            int grow = t * 64 + row;
            pre[it] = (grow < N_NODES) ? *(const float4*)(x + (size_t)grow * IN_DIM + sc4 * 4)
                                       : make_float4(0.f, 0.f, 0.f, 0.f);
        }
    }

    for (; t < NTILES; t += PBLK) {
        __syncthreads();
        #pragma unroll
        for (int it = 0; it < 4; ++it) {
            int row = it * 16 + srow;
            __bf16* dst = &xs[row][sc4 * 4];
            dst[0] = (__bf16)pre[it].x; dst[1] = (__bf16)pre[it].y;
            dst[2] = (__bf16)pre[it].z; dst[3] = (__bf16)pre[it].w;
        }
        __syncthreads();

        int tn = t + PBLK;
        if (tn < NTILES) {
            #pragma unroll
            for (int it = 0; it < 4; ++it) {
                int row  = it * 16 + srow;
                int grow = tn * 64 + row;
                pre[it] = (grow < N_NODES) ? *(const float4*)(x + (size_t)grow * IN_DIM + sc4 * 4)
                                           : make_float4(0.f, 0.f, 0.f, 0.f);
            }
        }

        f32x4 acc[4][4];
        #pragma unroll
        for (int i = 0; i < 4; ++i)
            #pragma unroll
            for (int j = 0; j < 4; ++j) acc[i][j] = (f32x4){0.f, 0.f, 0.f, 0.f};

        #pragma unroll
        for (int ks = 0; ks < 4; ++ks) {
            #pragma unroll
            for (int rf = 0; rf < 4; ++rf) {
                bf16x8 A = *(const bf16x8*)&xs[rf * 16 + l15][ks * 32 + g * 8];
                #pragma unroll
                for (int cf = 0; cf < 4; ++cf)
                    acc[rf][cf] = __builtin_amdgcn_mfma_f32_16x16x32_bf16(A, Bf[ks][cf], acc[rf][cf], 0, 0, 0);
            }
        }

        const int nodebase = t * 64;
        if (p == 0 || p == 3) {
            __bf16* outp = (p == 0) ? qb : sbuf;
            #pragma unroll
            for (int cf = 0; cf < 4; ++cf) {
                int col = colh + cf * 16 + l15;
                #pragma unroll
                for (int rf = 0; rf < 4; ++rf) {
                    #pragma unroll
                    for (int r = 0; r < 4; ++r) {
                        int grow = nodebase + rf * 16 + g * 4 + r;
                        if (grow < N_NODES)
                            outp[(size_t)grow * HD + col] = (__bf16)(acc[rf][cf][r] + bias_v[cf]);
                    }
                }
            }
        } else {
            unsigned char* outp = kv8 + ((p == 2) ? 128 : 0);
            #pragma unroll
            for (int cf = 0; cf < 4; ++cf) {
                int col = colh + cf * 16 + l15;
                #pragma unroll
                for (int rf = 0; rf < 4; ++rf) {
                    #pragma unroll
                    for (int r = 0; r < 4; ++r) {
                        int grow = nodebase + rf * 16 + g * 4 + r;
                        if (grow < N_NODES) {
                            float val = acc[rf][cf][r] + bias_v[cf];
                            unsigned int pk = __builtin_amdgcn_cvt_pk_fp8_f32(val, val, 0, false);
                            outp[(size_t)grow * 256 + col] = (unsigned char)(pk & 0xff);
                        }
                    }
                }
            }
        }
    }
}

// ---------------------------------------------------------------------------
// Pass B1: one block per bin. Parallel exclusive scan of NBLK_AC counts.
// ---------------------------------------------------------------------------
__global__ __launch_bounds__(256) void scanB1(
    int* __restrict__ hist, int* __restrict__ sums)
{
    __shared__ int a[512];
    const int tid = threadIdx.x;
    const int b   = blockIdx.x;
    int* hb = hist + (size_t)b * NBLK_AC;

    a[tid]       = (tid       < NBLK_AC) ? hb[tid]       : 0;
    a[tid + 256] = (tid + 256 < NBLK_AC) ? hb[tid + 256] : 0;
    __syncthreads();
    #pragma unroll
    for (int d = 1; d < 512; d <<= 1) {
        int v0 = a[tid],       u0 = (tid       >= d) ? a[tid - d]       : 0;
        int v1 = a[tid + 256], u1 = (tid + 256 >= d) ? a[tid + 256 - d] : 0;
        __syncthreads();
        a[tid] = v0 + u0; a[tid + 256] = v1 + u1;
        __syncthreads();
    }
    if (tid < NBLK_AC)       hb[tid]       = (tid == 0) ? 0 : a[tid - 1];
    if (tid + 256 < NBLK_AC) hb[tid + 256] = a[tid + 255];
    if (tid == 0) sums[b] = a[NBLK_AC - 1];
}

// ---------------------------------------------------------------------------
// Pass B2: single block, parallel exclusive scan over NB bin sums -> binbase.
// ---------------------------------------------------------------------------
__global__ __launch_bounds__(256) void scanB2(
    const int* __restrict__ sums, int* __restrict__ binbase)
{
    __shared__ int a[256];
    const int tid = threadIdx.x;
    a[tid] = (tid < NB) ? sums[tid] : 0;
    __syncthreads();
    #pragma unroll
    for (int d = 1; d < 256; d <<= 1) {
        int v = a[tid];
        int u = (tid >= d) ? a[tid - d] : 0;
        __syncthreads();
        a[tid] = v + u;
        __syncthreads();
    }
    if (tid < NB) binbase[tid] = (tid == 0) ? 0 : a[tid - 1];
    if (tid == 0) binbase[NB] = a[255];
}

// ---------------------------------------------------------------------------
// Pass C: scatter (src,dst) into bin-partitioned part[].
// ---------------------------------------------------------------------------
__global__ __launch_bounds__(256) void scatterC(
    const int* __restrict__ ei, const int* __restrict__ hist,
    const int* __restrict__ binbase, int2* __restrict__ part)
{
    __shared__ int hb[NB];
    __shared__ int h2[NB];
    const int tid = threadIdx.x;
    for (int i = tid; i < NB; i += 256) {
        hb[i] = hist[i * NBLK_AC + blockIdx.x] + binbase[i];
        h2[i] = 0;
    }
    __syncthreads();

    const int* srcs = ei;
    const int* dsts = ei + E_EDGES;
    const int base = blockIdx.x * EB;
    #pragma unroll
    for (int half = 0; half < 2; ++half) {
        int e0 = base + half * 1024 + tid * 4;
        if (e0 + 3 < E_EDGES) {
            int4 s4 = *(const int4*)(srcs + e0);
            int4 d4 = *(const int4*)(dsts + e0);
            int bin, r;
            bin = d4.x >> 8; r = atomicAdd(&h2[bin], 1); part[hb[bin] + r] = make_int2(s4.x, d4.x);
            bin = d4.y >> 8; r = atomicAdd(&h2[bin], 1); part[hb[bin] + r] = make_int2(s4.y, d4.y);
            bin = d4.z >> 8; r = atomicAdd(&h2[bin], 1); part[hb[bin] + r] = make_int2(s4.z, d4.z);
            bin = d4.w >> 8; r = atomicAdd(&h2[bin], 1); part[hb[bin] + r] = make_int2(s4.w, d4.w);
        } else {
            for (int j = 0; j < 4; ++j) {
                if (e0 + j < E_EDGES) {
                    int sv = srcs[e0 + j], dv = dsts[e0 + j];
                    int bin = dv >> 8;
                    int r = atomicAdd(&h2[bin], 1);
                    part[hb[bin] + r] = make_int2(sv, dv);
                }
            }
        }
    }
}

// ---------------------------------------------------------------------------
// Pass D: one block per bin. Exact per-node counts + scan -> compacted CSR.
// ---------------------------------------------------------------------------
__global__ __launch_bounds__(256) void buildD(
    const int2* __restrict__ part, const int* __restrict__ binbase,
    int* __restrict__ slot, int* __restrict__ nbase)
{
    __shared__ int cnt2[NPB];
    __shared__ int pfx[NPB];
    __shared__ int ofs[NPB];
    const int tid = threadIdx.x;
    const int b   = blockIdx.x;
    const int lo  = binbase[b];
    const int hi  = binbase[b + 1];
    const int n0  = b * NPB;

    cnt2[tid] = 0;
    __syncthreads();
    for (int i = lo + tid; i < hi; i += 256)
        atomicAdd(&cnt2[part[i].y - n0], 1);
    __syncthreads();

    pfx[tid] = cnt2[tid];
    __syncthreads();
    #pragma unroll
    for (int d = 1; d < NPB; d <<= 1) {
        int v = pfx[tid];
        int u = (tid >= d) ? pfx[tid - d] : 0;
        __syncthreads();
        pfx[tid] = v + u;
        __syncthreads();
    }
    const int excl = pfx[tid] - cnt2[tid];
    ofs[tid] = excl;
    const int node = n0 + tid;
    if (node < N_NODES) nbase[node] = lo + excl;
    if (b == NB - 1 && tid == 0) nbase[N_NODES] = E_EDGES;
    __syncthreads();

    for (int i = lo + tid; i < hi; i += 256) {
        int2 e = part[i];
        int r = atomicAdd(&ofs[e.y - n0], 1);
        slot[lo + r] = e.x;
    }
}

// ---------------------------------------------------------------------------
// Aggregation: wave = 2 nodes x 2 edge-slots; lane owns 8 cols; 8 edges/iter.
// Direct slot loads (16-lane same-address broadcast, no shfl). k/v fp8.
// ---------------------------------------------------------------------------
__global__ __launch_bounds__(256) void aggregate_kernel(
    const __bf16* __restrict__ qb, const unsigned char* __restrict__ kv8,
    const __bf16* __restrict__ sbuf,
    const int* __restrict__ nbase, const int* __restrict__ slot,
    float* __restrict__ out)
{
    const int tid  = threadIdx.x;
    const int lane = tid & 63;
    const int wave = tid >> 6;
    const int h    = lane >> 5;      // node of the pair
    const int lh   = lane & 31;
    const int s    = lh >> 4;        // edge slot (0/1)
    const int l16  = lh & 15;        // owns cols 8*l16 .. 8*l16+7
    const int node = blockIdx.x * 8 + wave * 2 + h;
    const bool nvalid = node < N_NODES;
    const int nc = nvalid ? node : 0;

    const int bse = nbase[nc];
    const int deg = nvalid ? (nbase[nc + 1] - bse) : 0;

    u16x8 qu = *(const u16x8*)(qb + (size_t)nc * HD + 8 * l16);
    float qf[8];
    #pragma unroll
    for (int c = 0; c < 8; ++c) qf[c] = bf2f(qu[c]);

    float lsum = 0.f;
    float acc[8];
    #pragma unroll
    for (int c = 0; c < 8; ++c) acc[c] = 0.f;

    for (int i = 0; i < deg; i += 8) {
        int  jj[4], se[4];
        uint2 kr[4], vr[4];
        float d[4];

        #pragma unroll
        for (int r = 0; r < 4; ++r) {
            jj[r] = i + 2 * r + s;                        // per-lane ordinal
            int sv = slot[bse + ((jj[r] < deg) ? jj[r] : 0)];  // same addr across 16 lanes
            se[r] = (jj[r] < deg) ? sv : 0;
        }
        #pragma unroll
        for (int r = 0; r < 4; ++r) {
            const unsigned char* rowp = kv8 + (size_t)se[r] * 256 + 8 * l16;
            kr[r] = *(const uint2*)rowp;           // k fp8 x8
            vr[r] = *(const uint2*)(rowp + 128);   // v fp8 x8
        }
        #pragma unroll
        for (int r = 0; r < 4; ++r) {
            f32x2 ka = __builtin_amdgcn_cvt_pk_f32_fp8(kr[r].x, 0);
            f32x2 kb_ = __builtin_amdgcn_cvt_pk_f32_fp8(kr[r].x, 1);
            f32x2 kc = __builtin_amdgcn_cvt_pk_f32_fp8(kr[r].y, 0);
            f32x2 kd = __builtin_amdgcn_cvt_pk_f32_fp8(kr[r].y, 1);
            d[r] = qf[0] * ka.x + qf[1] * ka.y + qf[2] * kb_.x + qf[3] * kb_.y
                 + qf[4] * kc.x + qf[5] * kc.y + qf[6] * kd.x + qf[7] * kd.y;
        }
        #pragma unroll
        for (int m = 1; m <= 4; m <<= 1) {
            d[0] += __shfl_xor(d[0], m);
            d[1] += __shfl_xor(d[1], m);
            d[2] += __shfl_xor(d[2], m);
            d[3] += __shfl_xor(d[3], m);
        }
        #pragma unroll
        for (int r = 0; r < 4; ++r) {
            float a2 = (jj[r] < deg) ? d[r] * PSCALE : -INFINITY;
            float p  = exp2f(a2);                // == exp(alpha), exp2(-inf)=0
            lsum += p;
            f32x2 va = __builtin_amdgcn_cvt_pk_f32_fp8(vr[r].x, 0);
            f32x2 vb_ = __builtin_amdgcn_cvt_pk_f32_fp8(vr[r].x, 1);
            f32x2 vc = __builtin_amdgcn_cvt_pk_f32_fp8(vr[r].y, 0);
            f32x2 vd = __builtin_amdgcn_cvt_pk_f32_fp8(vr[r].y, 1);
            acc[0] += p * va.x;  acc[1] += p * va.y;
            acc[2] += p * vb_.x; acc[3] += p * vb_.y;
            acc[4] += p * vc.x;  acc[5] += p * vc.y;
            acc[6] += p * vd.x;  acc[7] += p * vd.y;
        }
    }

    lsum += __shfl_xor(lsum, 16);
    #pragma unroll
    for (int c = 0; c < 8; ++c) acc[c] += __shfl_xor(acc[c], 16);

    float inv = (deg > 0) ? 1.f / (lsum + 1e-16f) : 0.f;
    u16x8 su = *(const u16x8*)(sbuf + (size_t)nc * HD + 8 * l16);

    f32x4 ov;
    #pragma unroll
    for (int cc = 0; cc < 4; ++cc) {
        float av;
        unsigned short sv;
        switch (cc) {  // static indices; s-select via cndmask
            case 0: av = s ? acc[4] : acc[0]; sv = s ? su[4] : su[0]; break;
            case 1: av = s ? acc[5] : acc[1]; sv = s ? su[5] : su[1]; break;
            case 2: av = s ? acc[6] : acc[2]; sv = s ? su[6] : su[2]; break;
            default: av = s ? acc[7] : acc[3]; sv = s ? su[7] : su[3]; break;
        }
        ov[cc] = fmaxf(av * inv + bf2f(sv), 0.f);
    }
    if (nvalid)
        *(f32x4*)(out + (size_t)node * HD + 8 * l16 + 4 * s) = ov;
}

// ---------------------------------------------------------------------------
extern "C" void kernel_launch(void* const* d_in, const int* in_sizes, int n_in,
                              void* d_out, int out_size, void* d_ws, size_t ws_size,
                              hipStream_t stream)
{
    const float* x  = (const float*)d_in[0];
    const int*   ei = (const int*)d_in[1];
    const float* Wq = (const float*)d_in[2];
    const float* bq = (const float*)d_in[3];
    const float* Wk = (const float*)d_in[4];
    const float* bk = (const float*)d_in[5];
    const float* Wv = (const float*)d_in[6];
    const float* bv = (const float*)d_in[7];
    const float* Ws = (const float*)d_in[8];
    const float* bs = (const float*)d_in[9];

    char* ws = (char*)d_ws;
    size_t off = 0;
    auto alloc = [&](size_t bytes) {
        void* p = ws + off;
        off += (bytes + 255) & ~(size_t)255;
        return p;
    };
    const size_t projB = (size_t)N_NODES * HD * sizeof(__bf16);  // 12.8 MB
    __bf16* qb = (__bf16*)alloc(projB);
    unsigned char* kv8 = (unsigned char*)alloc((size_t)N_NODES * 256);
    __bf16* sbf = (__bf16*)alloc(projB);
    int* hist    = (int*)alloc((size_t)NB * NBLK_AC * sizeof(int));   // 306 KB
    int* sums    = (int*)alloc((size_t)NB * sizeof(int));
    int* binbase = (int*)alloc((size_t)(NB + 1) * sizeof(int));
    int2* part   = (int2*)alloc((size_t)E_EDGES * sizeof(int2));      // 6.4 MB
    int* slot    = (int*)alloc((size_t)E_EDGES * sizeof(int));        // 3.2 MB
    int* nbase   = (int*)alloc((size_t)(N_NODES + 1) * sizeof(int));  // 200 KB

    fused_proj_hist<<<PBLK + NBLK_AC, 512, 0, stream>>>(
        x, Wq, bq, Wk, bk, Wv, bv, Ws, bs, ei, hist, qb, kv8, sbf);

    scanB1<<<NB, 256, 0, stream>>>(hist, sums);
    scanB2<<<1, 256, 0, stream>>>(sums, binbase);
    scatterC<<<NBLK_AC, 256, 0, stream>>>(ei, hist, binbase, part);
    buildD<<<NB, 256, 0, stream>>>(part, binbase, slot, nbase);

    aggregate_kernel<<<(N_NODES + 7) / 8, 256, 0, stream>>>(
        qb, kv8, sbf, nbase, slot, (float*)d_out);
}